// Round 1
// baseline (167.510 us; speedup 1.0000x reference)
//
#include <hip/hip_runtime.h>

#define Bdim 2
#define Sdim 2048
#define Ddim 1024
#define Hdim 16

typedef unsigned short u16;
typedef u16 u16x8 __attribute__((ext_vector_type(8)));
typedef u16 u16x4 __attribute__((ext_vector_type(4)));
typedef __bf16 bf16x8 __attribute__((ext_vector_type(8)));
typedef float f32x4 __attribute__((ext_vector_type(4)));

static __device__ __forceinline__ u16 f2bf(float f) {
  unsigned u = __float_as_uint(f);
  u += 0x7fffu + ((u >> 16) & 1u);
  return (u16)(u >> 16);
}
static __device__ __forceinline__ bf16x8 asbf(u16x8 v) {
  return __builtin_bit_cast(bf16x8, v);
}
static __device__ __forceinline__ f32x4 mfma16(bf16x8 a, bf16x8 b, f32x4 c) {
  return __builtin_amdgcn_mfma_f32_16x16x32_bf16(a, b, c, 0, 0, 0);
}

// ---------------- cast x (f32 -> bf16), 8 elems/thread ----------------
__global__ __launch_bounds__(256) void cvtx(const float* __restrict__ x,
                                            u16* __restrict__ xb) {
  int i = blockIdx.x * 256 + threadIdx.x;
  const float4* xp = (const float4*)x;
  float4 a = xp[2 * i], b = xp[2 * i + 1];
  u16x8 o;
  o[0] = f2bf(a.x); o[1] = f2bf(a.y); o[2] = f2bf(a.z); o[3] = f2bf(a.w);
  o[4] = f2bf(b.x); o[5] = f2bf(b.y); o[6] = f2bf(b.z); o[7] = f2bf(b.w);
  ((u16x8*)xb)[i] = o;
}

// ---------------- transpose + cast W [K][N] f32 -> WT [N][K] bf16 ----------------
__global__ __launch_bounds__(256) void transw(
    const float* __restrict__ W0, const float* __restrict__ W1,
    const float* __restrict__ W2, const float* __restrict__ W3,
    u16* __restrict__ T0, u16* __restrict__ T1,
    u16* __restrict__ T2, u16* __restrict__ T3) {
  const float* W = blockIdx.z == 0 ? W0 : blockIdx.z == 1 ? W1 : blockIdx.z == 2 ? W2 : W3;
  u16* T = blockIdx.z == 0 ? T0 : blockIdx.z == 1 ? T1 : blockIdx.z == 2 ? T2 : T3;
  __shared__ float tile[32][33];
  const int t = threadIdx.x;
  const int k0 = blockIdx.x * 32, n0 = blockIdx.y * 32;
  const int r = t >> 3, cq = (t & 7) * 4;
  float4 v = *(const float4*)(W + (size_t)(k0 + r) * Ddim + n0 + cq);
  tile[r][cq] = v.x; tile[r][cq + 1] = v.y; tile[r][cq + 2] = v.z; tile[r][cq + 3] = v.w;
  __syncthreads();
  u16x4 ov;
  ov[0] = f2bf(tile[cq][r]);
  ov[1] = f2bf(tile[cq + 1][r]);
  ov[2] = f2bf(tile[cq + 2][r]);
  ov[3] = f2bf(tile[cq + 3][r]);
  *(u16x4*)(T + (size_t)(n0 + r) * Ddim + k0 + cq) = ov;
}

// ---------------- transpose V [B,S,D] bf16 -> VT [B*H][64][S] bf16 ----------------
__global__ __launch_bounds__(256) void vtrans(const u16* __restrict__ V,
                                              u16* __restrict__ VT) {
  __shared__ u16 tile[32][72];
  const int t = threadIdx.x;
  const int s0 = blockIdx.x * 32;
  const int bh = blockIdx.y, b = bh >> 4, h = bh & 15;
  {
    int sl = t >> 3, dq = (t & 7) * 8;
    u16x8 v = *(const u16x8*)(V + (size_t)(b * Sdim + s0 + sl) * Ddim + h * 64 + dq);
    *(u16x8*)(&tile[sl][dq]) = v;
  }
  __syncthreads();
  {
    int dl = t >> 2, sq = (t & 3) * 8;
    u16x8 v;
#pragma unroll
    for (int i = 0; i < 8; i++) v[i] = tile[sq + i][dl];
    *(u16x8*)(VT + ((size_t)bh * 64 + dl) * Sdim + s0 + sq) = v;
  }
}

// ---------------- 128x128 bf16 MFMA GEMM: C = A[M,1024] @ (Bt[N,1024])^T ----------------
// A row-major bf16, Bt row-major bf16 (Bt[n][k] = B[k][n]). 4 waves (2x2), each 64x64.
template <bool F32OUT>
__global__ __launch_bounds__(256) void gemm128(
    const u16* __restrict__ A,
    const u16* __restrict__ Bt0, const u16* __restrict__ Bt1, const u16* __restrict__ Bt2,
    void* __restrict__ C0v, void* __restrict__ C1v, void* __restrict__ C2v) {
  __shared__ u16 As[128 * 64];
  __shared__ u16 Bs[128 * 64];
  const u16* Bt = (blockIdx.z == 0) ? Bt0 : (blockIdx.z == 1) ? Bt1 : Bt2;
  void* Cv = (blockIdx.z == 0) ? C0v : (blockIdx.z == 1) ? C1v : C2v;

  const int t = threadIdx.x;
  const int lane = t & 63, w = t >> 6;
  const int wm = w >> 1, wn = w & 1;
  const int c = lane & 15, g = lane >> 4;
  const int m0 = blockIdx.x * 128, n0 = blockIdx.y * 128;

  const f32x4 zv = {0.f, 0.f, 0.f, 0.f};
  f32x4 acc[4][4];
#pragma unroll
  for (int m = 0; m < 4; m++)
#pragma unroll
    for (int n = 0; n < 4; n++) acc[m][n] = zv;

  for (int kt = 0; kt < 1024; kt += 64) {
    __syncthreads();
    // stage A,Bt tiles (128 rows x 64 k) with XOR chunk swizzle (T2)
#pragma unroll
    for (int i = 0; i < 4; i++) {
      int idx = t + 256 * i;  // 0..1023 chunk id
      int row = idx >> 3, ch = idx & 7;
      int sw = (ch ^ (row & 7)) * 8;
      u16x8 va = *(const u16x8*)(A + (size_t)(m0 + row) * 1024 + kt + ch * 8);
      *(u16x8*)(As + row * 64 + sw) = va;
      u16x8 vb = *(const u16x8*)(Bt + (size_t)(n0 + row) * 1024 + kt + ch * 8);
      *(u16x8*)(Bs + row * 64 + sw) = vb;
    }
    __syncthreads();
#pragma unroll
    for (int kh = 0; kh < 2; kh++) {
      bf16x8 af[4], bfr[4];
#pragma unroll
      for (int m = 0; m < 4; m++) {
        int row = wm * 64 + m * 16 + c;
        int ch = kh * 4 + g;
        af[m] = asbf(*(const u16x8*)(As + row * 64 + ((ch ^ (row & 7)) * 8)));
      }
#pragma unroll
      for (int n = 0; n < 4; n++) {
        int row = wn * 64 + n * 16 + c;
        int ch = kh * 4 + g;
        bfr[n] = asbf(*(const u16x8*)(Bs + row * 64 + ((ch ^ (row & 7)) * 8)));
      }
#pragma unroll
      for (int m = 0; m < 4; m++)
#pragma unroll
        for (int n = 0; n < 4; n++) acc[m][n] = mfma16(af[m], bfr[n], acc[m][n]);
    }
  }
  // epilogue: C/D layout col=lane&15, row=4*(lane>>4)+r  [measured m89/m91]
#pragma unroll
  for (int m = 0; m < 4; m++)
#pragma unroll
    for (int n = 0; n < 4; n++)
#pragma unroll
      for (int r = 0; r < 4; r++) {
        int row = m0 + wm * 64 + m * 16 + 4 * g + r;
        int col = n0 + wn * 64 + n * 16 + c;
        if (F32OUT)
          ((float*)Cv)[(size_t)row * 1024 + col] = acc[m][n][r];
        else
          ((u16*)Cv)[(size_t)row * 1024 + col] = f2bf(acc[m][n][r]);
      }
}

// ---------------- flash attention: 4 waves x 16 q-rows, key tiles of 32 ----------------
__global__ __launch_bounds__(256) void attn_kernel(
    const u16* __restrict__ Q, const u16* __restrict__ K,
    const u16* __restrict__ VT, const int* __restrict__ vlen,
    u16* __restrict__ O) {
  __shared__ u16 Pl[4][16][32];
  const int t = threadIdx.x;
  const int lane = t & 63, w = t >> 6;
  const int c = lane & 15, g = lane >> 4;
  const int bh = blockIdx.y, b = bh >> 4, h = bh & 15;
  const int q0 = blockIdx.x * 64 + w * 16;
  const int nv = vlen[b];

  const u16* qp = Q + (size_t)(b * Sdim + q0 + c) * Ddim + h * 64;
  bf16x8 qf0 = asbf(*(const u16x8*)(qp + 8 * g));
  bf16x8 qf1 = asbf(*(const u16x8*)(qp + 32 + 8 * g));

  const f32x4 zv = {0.f, 0.f, 0.f, 0.f};
  float mr[4], lr[4];
  f32x4 o[4];
#pragma unroll
  for (int r = 0; r < 4; r++) { mr[r] = -__builtin_inff(); lr[r] = 0.f; }
#pragma unroll
  for (int d = 0; d < 4; d++) o[d] = zv;

  const int ktiles = (nv + 31) >> 5;
  for (int kt = 0; kt < ktiles; kt++) {
    const int k0 = kt * 32;
    const u16* kp0 = K + (size_t)(b * Sdim + k0 + c) * Ddim + h * 64;
    const u16* kp1 = kp0 + (size_t)16 * Ddim;
    f32x4 s0 = zv, s1 = zv;
    s0 = mfma16(qf0, asbf(*(const u16x8*)(kp0 + 8 * g)), s0);
    s0 = mfma16(qf1, asbf(*(const u16x8*)(kp0 + 32 + 8 * g)), s0);
    s1 = mfma16(qf0, asbf(*(const u16x8*)(kp1 + 8 * g)), s1);
    s1 = mfma16(qf1, asbf(*(const u16x8*)(kp1 + 32 + 8 * g)), s1);

    const bool v0 = (k0 + c) < nv;
    const bool v1 = (k0 + 16 + c) < nv;
    float p0[4], p1[4];
#pragma unroll
    for (int r = 0; r < 4; r++) {
      float a0 = v0 ? s0[r] * 0.125f : -1e30f;
      float a1 = v1 ? s1[r] * 0.125f : -1e30f;
      float vmax = fmaxf(a0, a1);
      vmax = fmaxf(vmax, __shfl_xor(vmax, 1));
      vmax = fmaxf(vmax, __shfl_xor(vmax, 2));
      vmax = fmaxf(vmax, __shfl_xor(vmax, 4));
      vmax = fmaxf(vmax, __shfl_xor(vmax, 8));
      float nm = fmaxf(mr[r], vmax);
      float al = __expf(mr[r] - nm);  // first tile: exp(-inf)=0
      float e0 = __expf(a0 - nm);     // masked: exp(-1e30)=0
      float e1 = __expf(a1 - nm);
      float rs = e0 + e1;
      rs += __shfl_xor(rs, 1);
      rs += __shfl_xor(rs, 2);
      rs += __shfl_xor(rs, 4);
      rs += __shfl_xor(rs, 8);
      lr[r] = lr[r] * al + rs;
      mr[r] = nm;
      p0[r] = e0;
      p1[r] = e1;
#pragma unroll
      for (int d = 0; d < 4; d++) o[d][r] *= al;
    }
    // P (C-layout) -> LDS -> A-fragment layout for PV
#pragma unroll
    for (int r = 0; r < 4; r++) {
      Pl[w][4 * g + r][c] = f2bf(p0[r]);
      Pl[w][4 * g + r][16 + c] = f2bf(p1[r]);
    }
    asm volatile("s_waitcnt lgkmcnt(0)" ::: "memory");
    __builtin_amdgcn_sched_barrier(0);
    bf16x8 pa = asbf(*(const u16x8*)(&Pl[w][c][8 * g]));
    const u16* vp = VT + ((size_t)bh * 64 + c) * Sdim + k0 + 8 * g;
#pragma unroll
    for (int d = 0; d < 4; d++)
      o[d] = mfma16(pa, asbf(*(const u16x8*)(vp + (size_t)d * 16 * Sdim)), o[d]);
  }
#pragma unroll
  for (int d = 0; d < 4; d++)
#pragma unroll
    for (int r = 0; r < 4; r++) {
      size_t off = (size_t)(b * Sdim + q0 + 4 * g + r) * Ddim + h * 64 + d * 16 + c;
      O[off] = f2bf(o[d][r] / lr[r]);
    }
}

extern "C" void kernel_launch(void* const* d_in, const int* in_sizes, int n_in,
                              void* d_out, int out_size, void* d_ws, size_t ws_size,
                              hipStream_t stream) {
  const float* x = (const float*)d_in[0];
  const float* Wq = (const float*)d_in[1];
  const float* Wk = (const float*)d_in[2];
  const float* Wv = (const float*)d_in[3];
  const float* Wo = (const float*)d_in[4];
  const int* vl = (const int*)d_in[5];
  float* out = (float*)d_out;

  char* ws = (char*)d_ws;
  const size_t SZ_X = (size_t)Bdim * Sdim * Ddim * sizeof(u16);  // 8 MB
  const size_t SZ_W = (size_t)Ddim * Ddim * sizeof(u16);         // 2 MB
  u16* xb = (u16*)ws; ws += SZ_X;
  u16* WqT = (u16*)ws; ws += SZ_W;
  u16* WkT = (u16*)ws; ws += SZ_W;
  u16* WvT = (u16*)ws; ws += SZ_W;
  u16* WoT = (u16*)ws; ws += SZ_W;
  u16* Qb = (u16*)ws; ws += SZ_X;
  u16* Kb = (u16*)ws; ws += SZ_X;
  u16* Vb = (u16*)ws; ws += SZ_X;
  u16* VTb = (u16*)ws; ws += SZ_X;
  u16* Ob = (u16*)ws; ws += SZ_X;

  cvtx<<<dim3((Bdim * Sdim * Ddim) / (8 * 256)), 256, 0, stream>>>(x, xb);
  transw<<<dim3(32, 32, 4), 256, 0, stream>>>(Wq, Wk, Wv, Wo, WqT, WkT, WvT, WoT);
  gemm128<false><<<dim3(32, 8, 3), 256, 0, stream>>>(xb, WqT, WkT, WvT, Qb, Kb, Vb);
  vtrans<<<dim3(Sdim / 32, Bdim * Hdim), 256, 0, stream>>>(Vb, VTb);
  attn_kernel<<<dim3(Sdim / 64, Bdim * Hdim), 256, 0, stream>>>(Qb, Kb, VTb, vl, Ob);
  gemm128<true><<<dim3(32, 8, 1), 256, 0, stream>>>(Ob, WoT, WoT, WoT, out, out, out);
}

// Round 5
// 141.249 us; speedup vs baseline: 1.1859x; 1.1859x over previous
//
#include <hip/hip_runtime.h>

#define Bdim 2
#define Sdim 2048
#define Ddim 1024
#define Hdim 16

typedef unsigned short u16;
typedef u16 u16x8 __attribute__((ext_vector_type(8)));
typedef u16 u16x4 __attribute__((ext_vector_type(4)));
typedef unsigned u32x4 __attribute__((ext_vector_type(4)));
typedef __bf16 bf16x8 __attribute__((ext_vector_type(8)));
typedef float f32x4 __attribute__((ext_vector_type(4)));
typedef float f32x16 __attribute__((ext_vector_type(16)));

static __device__ __forceinline__ u16 f2bf(float f) {
  unsigned u = __float_as_uint(f);
  u += 0x7fffu + ((u >> 16) & 1u);
  return (u16)(u >> 16);
}
static __device__ __forceinline__ bf16x8 asbf(u16x8 v) {
  return __builtin_bit_cast(bf16x8, v);
}
static __device__ __forceinline__ f32x4 mfma16(bf16x8 a, bf16x8 b, f32x4 c) {
  return __builtin_amdgcn_mfma_f32_16x16x32_bf16(a, b, c, 0, 0, 0);
}
static __device__ __forceinline__ f32x16 mfma32(bf16x8 a, bf16x8 b, f32x16 c) {
  return __builtin_amdgcn_mfma_f32_32x32x16_bf16(a, b, c, 0, 0, 0);
}

// async global->LDS, 16B per lane (m97 lever). LDS dest = wave-uniform base + lane*16.
#define GLD16(gp, lp)                                                   \
  __builtin_amdgcn_global_load_lds(                                     \
      (const __attribute__((address_space(1))) void*)(gp),              \
      (__attribute__((address_space(3))) void*)(lp), 16, 0, 0)

// ---------------- cast x (f32 -> bf16), 8 elems/thread ----------------
__global__ __launch_bounds__(256) void cvtx(const float* __restrict__ x,
                                            u16* __restrict__ xb) {
  int i = blockIdx.x * 256 + threadIdx.x;
  const float4* xp = (const float4*)x;
  float4 a = xp[2 * i], b = xp[2 * i + 1];
  u16x8 o;
  o[0] = f2bf(a.x); o[1] = f2bf(a.y); o[2] = f2bf(a.z); o[3] = f2bf(a.w);
  o[4] = f2bf(b.x); o[5] = f2bf(b.y); o[6] = f2bf(b.z); o[7] = f2bf(b.w);
  ((u16x8*)xb)[i] = o;
}

// ---------------- transpose + cast W [K][N] f32 -> WT [N][K] bf16 ----------------
__global__ __launch_bounds__(256) void transw(
    const float* __restrict__ W0, const float* __restrict__ W1,
    const float* __restrict__ W2, const float* __restrict__ W3,
    u16* __restrict__ T0, u16* __restrict__ T1,
    u16* __restrict__ T2, u16* __restrict__ T3) {
  const float* W = blockIdx.z == 0 ? W0 : blockIdx.z == 1 ? W1 : blockIdx.z == 2 ? W2 : W3;
  u16* T = blockIdx.z == 0 ? T0 : blockIdx.z == 1 ? T1 : blockIdx.z == 2 ? T2 : T3;
  __shared__ float tile[32][33];
  const int t = threadIdx.x;
  const int k0 = blockIdx.x * 32, n0 = blockIdx.y * 32;
  const int r = t >> 3, cq = (t & 7) * 4;
  float4 v = *(const float4*)(W + (size_t)(k0 + r) * Ddim + n0 + cq);
  tile[r][cq] = v.x; tile[r][cq + 1] = v.y; tile[r][cq + 2] = v.z; tile[r][cq + 3] = v.w;
  __syncthreads();
  u16x4 ov;
  ov[0] = f2bf(tile[cq][r]);
  ov[1] = f2bf(tile[cq + 1][r]);
  ov[2] = f2bf(tile[cq + 2][r]);
  ov[3] = f2bf(tile[cq + 3][r]);
  *(u16x4*)(T + (size_t)(n0 + r) * Ddim + k0 + cq) = ov;
}

// ---------------- transpose V [B,S,D] bf16 -> VT [B*H][64][S] bf16 ----------------
__global__ __launch_bounds__(256) void vtrans(const u16* __restrict__ V,
                                              u16* __restrict__ VT) {
  __shared__ u16 tile[32][72];
  const int t = threadIdx.x;
  const int s0 = blockIdx.x * 32;
  const int bh = blockIdx.y, b = bh >> 4, h = bh & 15;
  {
    int sl = t >> 3, dq = (t & 7) * 8;
    u16x8 v = *(const u16x8*)(V + (size_t)(b * Sdim + s0 + sl) * Ddim + h * 64 + dq);
    *(u16x8*)(&tile[sl][dq]) = v;
  }
  __syncthreads();
  {
    int dl = t >> 2, sq = (t & 3) * 8;
    u16x8 v;
#pragma unroll
    for (int i = 0; i < 8; i++) v[i] = tile[sq + i][dl];
    *(u16x8*)(VT + ((size_t)bh * 64 + dl) * Sdim + s0 + sq) = v;
  }
}

// ---------------- 128x128 bf16 MFMA GEMM (m97 structure): C = A[M,1024] @ Bt^T ----------------
// global_load_lds width-16 staging, linear LDS dest + inverse-XOR-swizzled global
// source (rule #21), swizzled ds_read. 4 waves (2x2), each 64x64 of the tile.
template <bool F32OUT>
__global__ __launch_bounds__(256) void gemm128(
    const u16* __restrict__ A,
    const u16* __restrict__ Bt0, const u16* __restrict__ Bt1, const u16* __restrict__ Bt2,
    void* __restrict__ C0v, void* __restrict__ C1v, void* __restrict__ C2v) {
  __shared__ u16 As[128 * 64];
  __shared__ u16 Bs[128 * 64];
  const u16* Bt = (blockIdx.z == 0) ? Bt0 : (blockIdx.z == 1) ? Bt1 : Bt2;
  void* Cv = (blockIdx.z == 0) ? C0v : (blockIdx.z == 1) ? C1v : C2v;

  const int t = threadIdx.x;
  const int lane = t & 63, w = t >> 6;
  const int wm = w >> 1, wn = w & 1;
  const int c = lane & 15, g = lane >> 4;
  const int m0 = blockIdx.x * 128, n0 = blockIdx.y * 128;
  // Q projection gets the 1/sqrt(DH)=0.125 scale folded in (z==0 of the QKV gemm).
  const float oscale = (!F32OUT && blockIdx.z == 0) ? 0.125f : 1.0f;

  const f32x4 zv = {0.f, 0.f, 0.f, 0.f};
  f32x4 acc[4][4];
#pragma unroll
  for (int m = 0; m < 4; m++)
#pragma unroll
    for (int n = 0; n < 4; n++) acc[m][n] = zv;

  const int r8 = lane >> 3, ch = lane & 7;  // staging: 8 rows x 8 chunks per instr
  for (int kt = 0; kt < 1024; kt += 64) {
    __syncthreads();
#pragma unroll
    for (int i = 0; i < 4; i++) {
      int row = w * 32 + i * 8 + r8;
      int sw8 = ((ch ^ (row & 7)) * 8);  // inverse-swizzled SOURCE chunk
      GLD16(A + (size_t)(m0 + row) * 1024 + kt + sw8, As + (w * 32 + i * 8) * 64);
      GLD16(Bt + (size_t)(n0 + row) * 1024 + kt + sw8, Bs + (w * 32 + i * 8) * 64);
    }
    __syncthreads();  // drains vmcnt -> staged data visible
#pragma unroll
    for (int kh = 0; kh < 2; kh++) {
      bf16x8 af[4], bfr[4];
#pragma unroll
      for (int m = 0; m < 4; m++) {
        int row = wm * 64 + m * 16 + c;
        int chr = kh * 4 + g;
        af[m] = asbf(*(const u16x8*)(As + row * 64 + ((chr ^ (row & 7)) * 8)));
      }
#pragma unroll
      for (int n = 0; n < 4; n++) {
        int row = wn * 64 + n * 16 + c;
        int chr = kh * 4 + g;
        bfr[n] = asbf(*(const u16x8*)(Bs + row * 64 + ((chr ^ (row & 7)) * 8)));
      }
#pragma unroll
      for (int m = 0; m < 4; m++)
#pragma unroll
        for (int n = 0; n < 4; n++) acc[m][n] = mfma16(af[m], bfr[n], acc[m][n]);
    }
  }
  // epilogue: C/D layout col=lane&15, row=4*(lane>>4)+r  [measured m89/m91]
#pragma unroll
  for (int m = 0; m < 4; m++)
#pragma unroll
    for (int n = 0; n < 4; n++)
#pragma unroll
      for (int r = 0; r < 4; r++) {
        int row = m0 + wm * 64 + m * 16 + 4 * g + r;
        int col = n0 + wn * 64 + n * 16 + c;
        if (F32OUT)
          ((float*)Cv)[(size_t)row * 1024 + col] = acc[m][n][r];
        else
          ((u16*)Cv)[(size_t)row * 1024 + col] = f2bf(acc[m][n][r] * oscale);
      }
}

// ---------------- flash attention, swapped-operand 32x32 structure ----------------
// 1 wave/block, 32 queries/wave, KVBLK=64. QK^T computed as mfma(K,Q) so each lane
// holds 32 scores of ONE query (col=lane&31) -> in-register softmax + one shfl_xor(32).
// PV computed as mfma(VT,P) so O stays lane-local (col=query). P redistribution via
// v_cvt_pk_bf16_f32 + v_permlane32_swap_b32 (T12). Defer-max THR=8 (T13).
__global__ __launch_bounds__(64, 3) void attn_kernel(
    const u16* __restrict__ Q, const u16* __restrict__ K,
    const u16* __restrict__ VT, const int* __restrict__ vlen,
    u16* __restrict__ O) {
  __shared__ u16 ot[32][72];
  const int lane = threadIdx.x;
  const int q = lane & 31, hi = lane >> 5;
  const int bh = blockIdx.y, b = bh >> 4, h = bh & 15;
  const int q0 = blockIdx.x * 32;
  const int nv = vlen[b];

  // Q fragments (Q pre-scaled by 0.125 in the projection GEMM)
  bf16x8 qf[4];
  {
    const u16* qp = Q + (size_t)(b * Sdim + q0 + q) * Ddim + h * 64 + hi * 8;
#pragma unroll
    for (int s = 0; s < 4; s++) qf[s] = asbf(*(const u16x8*)(qp + s * 16));
  }

  f32x16 o0, o1;
#pragma unroll
  for (int r = 0; r < 16; r++) { o0[r] = 0.f; o1[r] = 0.f; }
  float m = -3.0e38f, l = 0.f;

  const int ktiles = (nv + 63) >> 6;
  for (int kt = 0; kt < ktiles; ++kt) {
    const int k0 = kt * 64;
    // --- QK^T: A=K rows (key=lane&31), B=Q cols (query=lane&31) ---
    const u16* kp = K + (size_t)(b * Sdim + k0 + q) * Ddim + h * 64 + hi * 8;
    f32x16 sc[2];
#pragma unroll
    for (int kb = 0; kb < 2; kb++) {
      f32x16 acc;
#pragma unroll
      for (int r = 0; r < 16; r++) acc[r] = 0.f;
#pragma unroll
      for (int s = 0; s < 4; s++) {
        bf16x8 kf = asbf(*(const u16x8*)(kp + (size_t)kb * 32 * Ddim + s * 16));
        acc = mfma32(kf, qf[s], acc);
      }
      sc[kb] = acc;
    }
    // --- mask (tail tile only); key = k0+kb*32+crow(r,hi) ---
    if (k0 + 64 > nv) {
#pragma unroll
      for (int kb = 0; kb < 2; kb++)
#pragma unroll
        for (int r = 0; r < 16; r++) {
          int key = k0 + kb * 32 + (r & 3) + 8 * (r >> 2) + 4 * hi;
          if (key >= nv) sc[kb][r] = -1e30f;
        }
    }
    // --- row max: tree over 32 in-register + partner lane ---
    float mx[16];
#pragma unroll
    for (int r = 0; r < 16; r++) mx[r] = fmaxf(sc[0][r], sc[1][r]);
#pragma unroll
    for (int st = 8; st > 0; st >>= 1)
#pragma unroll
      for (int r = 0; r < st; r++) mx[r] = fmaxf(mx[r], mx[r + st]);
    float tm = fmaxf(mx[0], __shfl_xor(mx[0], 32));
    // --- defer-max (T13): rescale only when max grew by >8 ---
    if (!__all(tm <= m + 8.f)) {
      float mn = fmaxf(m, tm);
      float al = __expf(m - mn);
#pragma unroll
      for (int r = 0; r < 16; r++) { o0[r] *= al; o1[r] *= al; }
      l *= al;
      m = mn;
    }
    // --- P = exp(sc - m), packed straight to bf16 pairs (cvt_pk) ---
    unsigned pw[4][4];
    float s0 = 0.f, s1 = 0.f, s2 = 0.f, s3 = 0.f;
#pragma unroll
    for (int kb = 0; kb < 2; kb++)
#pragma unroll
      for (int hh = 0; hh < 2; hh++)
#pragma unroll
        for (int wi = 0; wi < 4; wi++) {
          float e0 = __expf(sc[kb][hh * 8 + wi * 2] - m);
          float e1 = __expf(sc[kb][hh * 8 + wi * 2 + 1] - m);
          if (wi == 0) s0 += e0 + e1;
          else if (wi == 1) s1 += e0 + e1;
          else if (wi == 2) s2 += e0 + e1;
          else s3 += e0 + e1;
          asm("v_cvt_pk_bf16_f32 %0, %1, %2"
              : "=v"(pw[kb * 2 + hh][wi]) : "v"(e0), "v"(e1));
        }
    float ssum = (s0 + s1) + (s2 + s3);
    ssum += __shfl_xor(ssum, 32);
    l += ssum;
    // --- redistribute P into B-fragment layout: 2 permlane32_swap per frag ---
#pragma unroll
    for (int f = 0; f < 4; f++) {
      asm("v_permlane32_swap_b32 %0, %1" : "+v"(pw[f][0]), "+v"(pw[f][2]));
      asm("v_permlane32_swap_b32 %0, %1" : "+v"(pw[f][1]), "+v"(pw[f][3]));
    }
    // --- PV as O^T = VT @ P: A=VT rows (dh=lane&31), B=P cols (query=lane&31) ---
    const u16* vp = VT + ((size_t)bh * 64 + q) * Sdim + k0 + hi * 8;
#pragma unroll
    for (int f = 0; f < 4; f++) {
      u32x4 wv = {pw[f][0], pw[f][1], pw[f][2], pw[f][3]};
      bf16x8 pa = __builtin_bit_cast(bf16x8, wv);
      o0 = mfma32(asbf(*(const u16x8*)(vp + f * 16)), pa, o0);
      o1 = mfma32(asbf(*(const u16x8*)(vp + (size_t)32 * Sdim + f * 16)), pa, o1);
    }
  }
  // --- epilogue: normalize (lane-local l), transpose via LDS, coalesced store ---
  const float linv = 1.f / l;
#pragma unroll
  for (int r = 0; r < 16; r++) {
    const int dh = (r & 3) + 8 * (r >> 2) + 4 * hi;
    ot[q][dh] = f2bf(o0[r] * linv);
    ot[q][32 + dh] = f2bf(o1[r] * linv);
  }
  asm volatile("s_waitcnt lgkmcnt(0)" ::: "memory");
  __builtin_amdgcn_sched_barrier(0);
  {
    u16* op = O + (size_t)(b * Sdim + q0 + q) * Ddim + h * 64 + hi * 32;
#pragma unroll
    for (int j = 0; j < 4; j++)
      *(u16x8*)(op + j * 8) = *(const u16x8*)(&ot[q][hi * 32 + j * 8]);
  }
}

extern "C" void kernel_launch(void* const* d_in, const int* in_sizes, int n_in,
                              void* d_out, int out_size, void* d_ws, size_t ws_size,
                              hipStream_t stream) {
  const float* x = (const float*)d_in[0];
  const float* Wq = (const float*)d_in[1];
  const float* Wk = (const float*)d_in[2];
  const float* Wv = (const float*)d_in[3];
  const float* Wo = (const float*)d_in[4];
  const int* vl = (const int*)d_in[5];
  float* out = (float*)d_out;

  char* ws = (char*)d_ws;
  const size_t SZ_X = (size_t)Bdim * Sdim * Ddim * sizeof(u16);  // 8 MB
  const size_t SZ_W = (size_t)Ddim * Ddim * sizeof(u16);         // 2 MB
  u16* xb = (u16*)ws; ws += SZ_X;
  u16* WqT = (u16*)ws; ws += SZ_W;
  u16* WkT = (u16*)ws; ws += SZ_W;
  u16* WvT = (u16*)ws; ws += SZ_W;
  u16* WoT = (u16*)ws; ws += SZ_W;
  u16* Qb = (u16*)ws; ws += SZ_X;
  u16* Kb = (u16*)ws; ws += SZ_X;
  u16* Vb = (u16*)ws; ws += SZ_X;
  u16* VTb = (u16*)ws; ws += SZ_X;
  u16* Ob = (u16*)ws; ws += SZ_X;

  cvtx<<<dim3((Bdim * Sdim * Ddim) / (8 * 256)), 256, 0, stream>>>(x, xb);
  transw<<<dim3(32, 32, 4), 256, 0, stream>>>(Wq, Wk, Wv, Wo, WqT, WkT, WvT, WoT);
  gemm128<false><<<dim3(32, 8, 3), 256, 0, stream>>>(xb, WqT, WkT, WvT, Qb, Kb, Vb);
  vtrans<<<dim3(Sdim / 32, Bdim * Hdim), 256, 0, stream>>>(Vb, VTb);
  attn_kernel<<<dim3(Sdim / 32, Bdim * Hdim), 64, 0, stream>>>(Qb, Kb, VTb, vl, Ob);
  gemm128<true><<<dim3(32, 8, 1), 256, 0, stream>>>(Ob, WoT, WoT, WoT, out, out, out);
}